// Round 12
// baseline (1806.181 us; speedup 1.0000x reference)
//
#include <hip/hip_runtime.h>
#include <cstdint>
#include <cstddef>

// Problem constants
#define NB    64      // batch
#define NS    4096    // seq len
#define NH    1024    // hidden
#define NOPSN 8
#define NSTEP 10

// Workspace layout (float offsets), ~2.2 MB.
// hn/hnT double-buffered by step parity; hnT = k-pair interleave:
// element (k,b) at [(k>>1)*128 + b*2 + (k&1)]
#define OFF_HN0  0u
#define OFF_HN1  65536u
#define OFF_HT0  131072u
#define OFF_HT1  196608u
#define OFF_H    262144u
#define OFF_CAND 327680u   // cand [64 b][512 blk] float2 (val, idx-as-float)
#define OFF_OPP  393216u   // opp [10][32 jg32][64 b][8 o]  (jg32 = 32-j groups)
#define OFF_CTRL 557056u   // ints: [2..11]=stopcnt[t]

typedef float f2v  __attribute__((ext_vector_type(2)));
typedef float f4v  __attribute__((ext_vector_type(4)));
typedef float f8v  __attribute__((ext_vector_type(8)));

__device__ __forceinline__ float bcastf(float v, int l) {
  return __int_as_float(__builtin_amdgcn_readlane(__float_as_int(v), l));
}

// ============ INIT: hn(0)=0.01*noise[0], hnT(0), h=0, opp[0], ctrl=0 ======
// grid 64 (block = b), 1024 threads (thread = j).
__global__ void __launch_bounds__(1024)
init_kernel(const float* __restrict__ noise, const float* __restrict__ Wop,
            float* __restrict__ wsf)
{
  const int b = blockIdx.x, j = threadIdx.x;
  const int jg32 = j >> 5;                 // 32-j group
  int* ctrl = (int*)(wsf + OFF_CTRL);
  if (b == 0 && j < NSTEP) ctrl[2 + j] = 0;

  float hv = 0.01f * noise[(size_t)b * NH + j];
  (wsf + OFF_HN0)[(size_t)b * NH + j] = hv;
  (wsf + OFF_HT0)[((size_t)(j >> 1)) * 128 + b * 2 + (j & 1)] = hv;
  (wsf + OFF_H)[(size_t)b * NH + j] = 0.f;

  const float* wrp = Wop + (size_t)j * NOPSN;
  float opo[8];
  #pragma unroll
  for (int o = 0; o < 8; ++o) opo[o] = hv * wrp[o];
  #pragma unroll
  for (int off = 1; off <= 16; off <<= 1) {         // reduce within 32-j group
    #pragma unroll
    for (int o = 0; o < 8; ++o) opo[o] += __shfl_xor(opo[o], off);
  }
  if ((j & 31) == 0) {
    float* od = (wsf + OFF_OPP) + (size_t)jg32 * 512 + (size_t)b * 8;
    #pragma unroll
    for (int o = 0; o < 8; ++o) od[o] = opo[o];
  }
}

// ============ PHASE A: x_logits[8 s][64 b] + cand + op-argmax =============
// grid 512 (block = 8 s-cols), 1024 thr, 32 KB LDS -> 2 blocks/CU,
// 8 waves/SIMD. lane = b; wave = 64-k slice. (R11-verified body; op-argmax
// adapted to the 32-group opp layout.)
__global__ void __launch_bounds__(1024, 8)
phaseA_kernel(const float* __restrict__ Wx, const float* __restrict__ bx,
              const float* __restrict__ bop, float* __restrict__ wsf, int st)
{
  __shared__ float smem[8192];   // 32 KB: [16 w][8 s][64 b]
  int* ctrl = (int*)(wsf + OFF_CTRL);
  float* __restrict__ opp = wsf + OFF_OPP;
  const float* __restrict__ hnT_cur = wsf + ((st & 1) ? OFF_HT1 : OFF_HT0);

  const int tid = threadIdx.x, blk = blockIdx.x;
  const int lane = tid & 63;
  const int wv = __builtin_amdgcn_readfirstlane(tid >> 6);
  const int s0A = blk << 3;
  const int kbaseA = wv << 6;

  const float2* hb = (const float2*)hnT_cur + ((size_t)(kbaseA >> 1)) * 64 + lane;

  // op-argmax for step st (blocks 0..63, wave 0)
  if (blk < NB && tid < 64) {
    const float* ob = opp + (size_t)st * 16384 + (size_t)blk * 8;
    const int o = lane & 7, jgb = lane >> 3;        // jgb 0..7
    float v = 0.f;
    #pragma unroll
    for (int m = 0; m < 4; ++m)                     // 4 groups per lane
      v += ob[(size_t)(jgb + 8 * m) * 512 + o];
    v += __shfl_xor(v, 8);
    v += __shfl_xor(v, 16);
    v += __shfl_xor(v, 32);
    v += bop[o];
    float bv = bcastf(v, 0); int bo = 0;
    #pragma unroll
    for (int oo = 1; oo < 8; ++oo) {
      float vo = bcastf(v, oo);
      if (vo > bv) { bv = vo; bo = oo; }            // strict > : first-max
    }
    if (lane == 0 && bo == 0) atomicAdd(&ctrl[2 + st], 1);
  }

  float acc[8];
  #pragma unroll
  for (int s = 0; s < 8; ++s) acc[s] = 0.f;

  #pragma unroll 1
  for (int c = 0; c < 4; ++c) {
    float2 hh[8];
    #pragma unroll
    for (int i = 0; i < 8; ++i) hh[i] = hb[(size_t)(c * 8 + i) * 64];
    #pragma unroll
    for (int i = 0; i < 8; ++i) {
      const int k = kbaseA + (c * 8 + i) * 2;
      const f8v w0 = *(const f8v*)(Wx + (size_t)k * NS + s0A);
      const f8v w1 = *(const f8v*)(Wx + (size_t)(k + 1) * NS + s0A);
      #pragma unroll
      for (int s = 0; s < 8; ++s)
        acc[s] += w0[s] * hh[i].x + w1[s] * hh[i].y;
    }
  }

  // cross-wave K reduction: red[16 w][8 s][64 b]
  #pragma unroll
  for (int s = 0; s < 8; ++s)
    smem[wv * 512 + s * 64 + lane] = acc[s];
  __syncthreads();
  {
    const int s = tid >> 6, b = tid & 63;           // s in [0,16), valid < 8
    float val = 0.f;
    if (s < 8) {
      val = bx[s0A + s];
      #pragma unroll
      for (int w = 0; w < 16; ++w) val += smem[w * 512 + s * 64 + b];
    }
    __syncthreads();
    if (s < 8) smem[s * 64 + b] = val;
    __syncthreads();
    if (tid < 64) {
      const int bb = tid;
      float bv = smem[bb]; int bs = 0;
      #pragma unroll
      for (int s2 = 1; s2 < 8; ++s2) {
        float v2 = smem[s2 * 64 + bb];
        if (v2 > bv) { bv = v2; bs = s2; }          // ascending s: first-max
      }
      float2* cp = (float2*)(wsf + OFF_CAND);
      cp[bb * 512 + blk] = make_float2(bv, __int_as_float(s0A + bs));
    }
  }
}

// ============ PHASE C: h_new + freeze + next hn/hnT/opp (+ out) ===========
// grid 512: block (jg: 32 j, bg: 4 b), 1024 thr, 16 KB LDS -> 2 blocks/CU.
// Wave wv owns 128 k; lane = (jloc 0..31, kh 0..1) -> 64 k x 4 b per thread.
// Halves per-block Wres slice (256 KB) and per-thread weight-load count
// vs the 64jx2b tiling.
__global__ void __launch_bounds__(1024, 8)
phaseC_kernel(const float* __restrict__ s2a,  const float* __restrict__ Wres,
              const float* __restrict__ bres, const float* __restrict__ Wop,
              const float* __restrict__ noise, float* __restrict__ out,
              float* __restrict__ wsf, int st)
{
  __shared__ float smem[4096];   // 16 KB: [32 partial][4 b][32 j]
  int* ctrl = (int*)(wsf + OFF_CTRL);
  float* __restrict__ h   = wsf + OFF_H;
  float* __restrict__ opp = wsf + OFF_OPP;
  const float* __restrict__ hn_cur = wsf + ((st & 1) ? OFF_HN1 : OFF_HN0);
  float* __restrict__       hn_nxt = wsf + ((st & 1) ? OFF_HN0 : OFF_HN1);
  float* __restrict__      hnT_nxt = wsf + ((st & 1) ? OFF_HT0 : OFF_HT1);

  const int tid = threadIdx.x, blk = blockIdx.x;
  const int lane = tid & 63;
  const int wv = __builtin_amdgcn_readfirstlane(tid >> 6);
  const int jg = blk & 31, bg = blk >> 5;          // jg: 32 groups, bg: 16
  const int j0 = jg << 5, b0 = bg << 2;            // 32 j, 4 b per block

  int ptrs[4] = {0, 0, 0, 0};
  if (wv >= 8) {                                   // only s2a half needs ptrs
    const float2* cp = (const float2*)(wsf + OFF_CAND);
    #pragma unroll
    for (int i = 0; i < 4; ++i) {
      const float2* row = cp + (size_t)(b0 + i) * 512;
      float2 c0 = row[lane];
      float bv = c0.x; int bi = __float_as_int(c0.y);
      #pragma unroll
      for (int q = 1; q < 8; ++q) {
        float2 c = row[q * 64 + lane];
        if (c.x > bv) { bv = c.x; bi = __float_as_int(c.y); }
      }
      #pragma unroll
      for (int off = 1; off <= 32; off <<= 1) {
        float ov = __shfl_xor(bv, off);
        int   oi = __shfl_xor(bi, off);
        if (ov > bv || (ov == bv && oi < bi)) { bv = ov; bi = oi; }
      }
      ptrs[i] = __builtin_amdgcn_readfirstlane(bi);
    }
  }
  int done = 0;
  for (int tt = 0; tt < st; ++tt) done |= (ctrl[2 + tt] == NB) ? 1 : 0;

  const int jloc = lane & 31, kh = lane >> 5;
  const int kb = (wv << 7) + (kh << 6);            // 64 k per thread
  const float *p0, *p1, *p2, *p3;                  // half-wave-uniform bases
  if (wv < 8) {
    p0 = hn_cur + (size_t)(b0 + 0) * NH + kb;
    p1 = hn_cur + (size_t)(b0 + 1) * NH + kb;
    p2 = hn_cur + (size_t)(b0 + 2) * NH + kb;
    p3 = hn_cur + (size_t)(b0 + 3) * NH + kb;
  } else {
    p0 = s2a + ((size_t)(b0 + 0) * NS + ptrs[0]) * NH + (kb - NH);
    p1 = s2a + ((size_t)(b0 + 1) * NS + ptrs[1]) * NH + (kb - NH);
    p2 = s2a + ((size_t)(b0 + 2) * NS + ptrs[2]) * NH + (kb - NH);
    p3 = s2a + ((size_t)(b0 + 3) * NS + ptrs[3]) * NH + (kb - NH);
  }
  const float* wp = Wres + (size_t)kb * NH + j0 + jloc;   // per-lane

  float a0 = 0.f, a1 = 0.f, a2 = 0.f, a3 = 0.f;

  #pragma unroll 1
  for (int kc = 0; kc < 64; kc += 4) {
    float w[4];
    f4v q0, q1, q2, q3;
    #pragma unroll
    for (int i = 0; i < 4; ++i) w[i] = wp[(size_t)(kc + i) * NH];
    q0 = *(const f4v*)(p0 + kc);
    q1 = *(const f4v*)(p1 + kc);
    q2 = *(const f4v*)(p2 + kc);
    q3 = *(const f4v*)(p3 + kc);
    #pragma unroll
    for (int i = 0; i < 4; ++i) {
      const float wv_ = w[i];
      a0 += q0[i] * wv_;
      a1 += q1[i] * wv_;
      a2 += q2[i] * wv_;
      a3 += q3[i] * wv_;
    }
  }

  // cross-wave reduce: red[32 partial (wv,kh)][4 b][32 j]
  {
    const int p = (wv << 1) | kh;
    smem[p * 128 + 0 * 32 + jloc] = a0;
    smem[p * 128 + 1 * 32 + jloc] = a1;
    smem[p * 128 + 2 * 32 + jloc] = a2;
    smem[p * 128 + 3 * 32 + jloc] = a3;
  }
  __syncthreads();

  if (tid < 128) {
    const int bsel = tid >> 5, jl = tid & 31;
    float v = bres[j0 + jl];
    #pragma unroll
    for (int p = 0; p < 32; ++p) v += smem[p * 128 + bsel * 32 + jl];
    const int b = b0 + bsel, j = j0 + jl;
    float hold = h[(size_t)b * NH + j];
    float hout = done ? hold : v;
    h[(size_t)b * NH + j] = hout;
    if (st < NSTEP - 1) {
      float hnv = hout + 0.01f * noise[(size_t)(st + 1) * (NB * NH) + (size_t)b * NH + j];
      hn_nxt[(size_t)b * NH + j] = hnv;
      hnT_nxt[((size_t)(j >> 1)) * 128 + b * 2 + (j & 1)] = hnv;
      const float* wrp = Wop + (size_t)j * NOPSN;
      float opo[8];
      #pragma unroll
      for (int o = 0; o < 8; ++o) opo[o] = hnv * wrp[o];
      #pragma unroll
      for (int off = 1; off <= 16; off <<= 1) {     // reduce within 32-j group
        #pragma unroll
        for (int o = 0; o < 8; ++o) opo[o] += __shfl_xor(opo[o], off);
      }
      if (jl == 0) {
        float* od = opp + ((size_t)(st + 1) * 32 + jg) * 512 + (size_t)b * 8;
        #pragma unroll
        for (int o = 0; o < 8; ++o) od[o] = opo[o];
      }
    } else {
      out[(size_t)b * NH + j] = hout;
    }
  }
}

extern "C" void kernel_launch(void* const* d_in, const int* in_sizes, int n_in,
                              void* d_out, int out_size, void* d_ws, size_t ws_size,
                              hipStream_t stream) {
  const float* s2a   = (const float*)d_in[0];
  const float* Wres  = (const float*)d_in[1];
  const float* bres  = (const float*)d_in[2];
  const float* Wop   = (const float*)d_in[3];
  const float* bop   = (const float*)d_in[4];
  const float* Wx    = (const float*)d_in[5];
  const float* bx    = (const float*)d_in[6];
  const float* noise = (const float*)d_in[7];
  float* outp = (float*)d_out;
  float* wsf  = (float*)d_ws;   // needs ~2.3 MB

  hipLaunchKernelGGL(init_kernel, dim3(64), dim3(1024), 0, stream,
                     noise, Wop, wsf);
  for (int st = 0; st < NSTEP; ++st) {
    hipLaunchKernelGGL(phaseA_kernel, dim3(512), dim3(1024), 0, stream,
                       Wx, bx, bop, wsf, st);
    hipLaunchKernelGGL(phaseC_kernel, dim3(512), dim3(1024), 0, stream,
                       s2a, Wres, bres, Wop, noise, outp, wsf, st);
  }
}

// Round 13
// 1798.676 us; speedup vs baseline: 1.0042x; 1.0042x over previous
//
#include <hip/hip_runtime.h>
#include <cstdint>
#include <cstddef>

// Problem constants
#define NB    64      // batch
#define NS    4096    // seq len
#define NH    1024    // hidden
#define NOPSN 8
#define NSTEP 10

// Workspace layout (float offsets), ~1.9 MB (R11-verified).
// hn/hnT double-buffered by step parity; hnT = k-pair interleave:
// element (k,b) at [(k>>1)*128 + b*2 + (k&1)]
#define OFF_HN0  0u
#define OFF_HN1  65536u
#define OFF_HT0  131072u
#define OFF_HT1  196608u
#define OFF_H    262144u
#define OFF_CAND 327680u   // cand [64 b][512 blk] float2 (val, idx-as-float)
#define OFF_OPP  393216u   // opp [10][16 jg][64 b][8 o]
#define OFF_CTRL 475136u   // ints: [2..11]=stopcnt[t]

typedef float f2v  __attribute__((ext_vector_type(2)));
typedef float f4v  __attribute__((ext_vector_type(4)));
typedef float f8v  __attribute__((ext_vector_type(8)));

__device__ __forceinline__ float bcastf(float v, int l) {
  return __int_as_float(__builtin_amdgcn_readlane(__float_as_int(v), l));
}

// ============ INIT: hn(0)=0.01*noise[0], hnT(0), h=0, opp[0], ctrl=0 ======
// grid 64 (block = b), 1024 threads (thread = j). Wave wv == jg.
__global__ void __launch_bounds__(1024)
init_kernel(const float* __restrict__ noise, const float* __restrict__ Wop,
            float* __restrict__ wsf)
{
  const int b = blockIdx.x, j = threadIdx.x;
  const int lane = j & 63, jg = j >> 6;
  int* ctrl = (int*)(wsf + OFF_CTRL);
  if (b == 0 && j < NSTEP) ctrl[2 + j] = 0;

  float hv = 0.01f * noise[(size_t)b * NH + j];
  (wsf + OFF_HN0)[(size_t)b * NH + j] = hv;
  (wsf + OFF_HT0)[((size_t)(j >> 1)) * 128 + b * 2 + (j & 1)] = hv;
  (wsf + OFF_H)[(size_t)b * NH + j] = 0.f;

  const float* wrp = Wop + (size_t)j * NOPSN;
  float opo[8];
  #pragma unroll
  for (int o = 0; o < 8; ++o) opo[o] = hv * wrp[o];
  #pragma unroll
  for (int off = 1; off <= 32; off <<= 1) {
    #pragma unroll
    for (int o = 0; o < 8; ++o) opo[o] += __shfl_xor(opo[o], off);
  }
  if (lane == 0) {
    float* od = (wsf + OFF_OPP) + (size_t)jg * 512 + (size_t)b * 8;
    #pragma unroll
    for (int o = 0; o < 8; ++o) od[o] = opo[o];
  }
}

// ============ PHASE A: x_logits[8 s][64 b] + cand + op-argmax =============
// grid 512 (block = 8 s-cols), 1024 thr, 32 KB LDS -> 2 blocks/CU,
// 8 waves/SIMD. lane = b; wave = 64-k slice. R11-verified body +
// next-chunk h prefetch (hides hnT L2 latency under FMAs).
__global__ void __launch_bounds__(1024, 8)
phaseA_kernel(const float* __restrict__ Wx, const float* __restrict__ bx,
              const float* __restrict__ bop, float* __restrict__ wsf, int st)
{
  __shared__ float smem[8192];   // 32 KB: [16 w][8 s][64 b]
  int* ctrl = (int*)(wsf + OFF_CTRL);
  float* __restrict__ opp = wsf + OFF_OPP;
  const float* __restrict__ hnT_cur = wsf + ((st & 1) ? OFF_HT1 : OFF_HT0);

  const int tid = threadIdx.x, blk = blockIdx.x;
  const int lane = tid & 63;
  const int wv = __builtin_amdgcn_readfirstlane(tid >> 6);
  const int s0A = blk << 3;
  const int kbaseA = wv << 6;

  const float2* hb = (const float2*)hnT_cur + ((size_t)(kbaseA >> 1)) * 64 + lane;

  // op-argmax for step st (blocks 0..63, wave 0)
  if (blk < NB && tid < 64) {
    const float* ob = opp + (size_t)st * 8192 + (size_t)blk * 8;
    const int o = lane & 7, jgb = lane >> 3;
    float v = ob[(size_t)jgb * 512 + o] + ob[(size_t)(jgb + 8) * 512 + o];
    v += __shfl_xor(v, 8);
    v += __shfl_xor(v, 16);
    v += __shfl_xor(v, 32);
    v += bop[o];
    float bv = bcastf(v, 0); int bo = 0;
    #pragma unroll
    for (int oo = 1; oo < 8; ++oo) {
      float vo = bcastf(v, oo);
      if (vo > bv) { bv = vo; bo = oo; }            // strict > : first-max
    }
    if (lane == 0 && bo == 0) atomicAdd(&ctrl[2 + st], 1);
  }

  float acc[8];
  #pragma unroll
  for (int s = 0; s < 8; ++s) acc[s] = 0.f;

  float2 hh[8], hp[8];
  #pragma unroll
  for (int i = 0; i < 8; ++i) hh[i] = hb[(size_t)i * 64];

  #pragma unroll 1
  for (int c = 0; c < 4; ++c) {
    if (c < 3) {                                    // prefetch next chunk's h
      #pragma unroll
      for (int i = 0; i < 8; ++i) hp[i] = hb[(size_t)((c + 1) * 8 + i) * 64];
    }
    #pragma unroll
    for (int i = 0; i < 8; ++i) {
      const int k = kbaseA + (c * 8 + i) * 2;
      const f8v w0 = *(const f8v*)(Wx + (size_t)k * NS + s0A);
      const f8v w1 = *(const f8v*)(Wx + (size_t)(k + 1) * NS + s0A);
      #pragma unroll
      for (int s = 0; s < 8; ++s)
        acc[s] += w0[s] * hh[i].x + w1[s] * hh[i].y;
    }
    if (c < 3) {
      #pragma unroll
      for (int i = 0; i < 8; ++i) hh[i] = hp[i];
    }
  }

  // cross-wave K reduction: red[16 w][8 s][64 b]
  #pragma unroll
  for (int s = 0; s < 8; ++s)
    smem[wv * 512 + s * 64 + lane] = acc[s];
  __syncthreads();
  {
    const int s = tid >> 6, b = tid & 63;           // s in [0,16), valid < 8
    float val = 0.f;
    if (s < 8) {
      val = bx[s0A + s];
      #pragma unroll
      for (int w = 0; w < 16; ++w) val += smem[w * 512 + s * 64 + b];
    }
    __syncthreads();
    if (s < 8) smem[s * 64 + b] = val;
    __syncthreads();
    if (tid < 64) {
      const int bb = tid;
      float bv = smem[bb]; int bs = 0;
      #pragma unroll
      for (int s2 = 1; s2 < 8; ++s2) {
        float v2 = smem[s2 * 64 + bb];
        if (v2 > bv) { bv = v2; bs = s2; }          // ascending s: first-max
      }
      float2* cp = (float2*)(wsf + OFF_CAND);
      cp[bb * 512 + blk] = make_float2(bv, __int_as_float(s0A + bs));
    }
  }
}

// ============ PHASE C: h_new + freeze + next hn/hnT/opp (+ out) ===========
// grid 512: block (jg: 64 j, bg: 2 b), 1024 thr, 8 KB LDS -> 2 blocks/CU.
// R11-verified body + next-chunk weight prefetch (8 extra VGPR, safe).
__global__ void __launch_bounds__(1024, 8)
phaseC_kernel(const float* __restrict__ s2a,  const float* __restrict__ Wres,
              const float* __restrict__ bres, const float* __restrict__ Wop,
              const float* __restrict__ noise, float* __restrict__ out,
              float* __restrict__ wsf, int st)
{
  __shared__ float smem[2048];   // 8 KB: [16 w][2 b][64 j]
  int* ctrl = (int*)(wsf + OFF_CTRL);
  float* __restrict__ h   = wsf + OFF_H;
  float* __restrict__ opp = wsf + OFF_OPP;
  const float* __restrict__ hn_cur = wsf + ((st & 1) ? OFF_HN1 : OFF_HN0);
  float* __restrict__       hn_nxt = wsf + ((st & 1) ? OFF_HN0 : OFF_HN1);
  float* __restrict__      hnT_nxt = wsf + ((st & 1) ? OFF_HT0 : OFF_HT1);

  const int tid = threadIdx.x, blk = blockIdx.x;
  const int lane = tid & 63;
  const int wv = __builtin_amdgcn_readfirstlane(tid >> 6);
  const int jg = blk & 15, bg = blk >> 4;          // bg in [0,32)
  const int j0 = jg << 6, b0 = bg << 1;            // 2 b per block

  int ptrs[2] = {0, 0};
  if (wv >= 8) {                                   // only s2a half needs ptrs
    const float2* cp = (const float2*)(wsf + OFF_CAND);
    #pragma unroll
    for (int i = 0; i < 2; ++i) {
      const float2* row = cp + (size_t)(b0 + i) * 512;
      float2 c0 = row[lane];
      float bv = c0.x; int bi = __float_as_int(c0.y);
      #pragma unroll
      for (int q = 1; q < 8; ++q) {
        float2 c = row[q * 64 + lane];
        if (c.x > bv) { bv = c.x; bi = __float_as_int(c.y); }
      }
      #pragma unroll
      for (int off = 1; off <= 32; off <<= 1) {
        float ov = __shfl_xor(bv, off);
        int   oi = __shfl_xor(bi, off);
        if (ov > bv || (ov == bv && oi < bi)) { bv = ov; bi = oi; }
      }
      ptrs[i] = __builtin_amdgcn_readfirstlane(bi);
    }
  }
  int done = 0;
  for (int tt = 0; tt < st; ++tt) done |= (ctrl[2 + tt] == NB) ? 1 : 0;

  const int kb = wv << 7;                          // 128 k per wave
  const float *p0, *p1;                            // wave-uniform bases
  if (wv < 8) {
    p0 = hn_cur + (size_t)(b0 + 0) * NH + kb;
    p1 = hn_cur + (size_t)(b0 + 1) * NH + kb;
  } else {
    p0 = s2a + ((size_t)(b0 + 0) * NS + ptrs[0]) * NH + (kb - NH);
    p1 = s2a + ((size_t)(b0 + 1) * NS + ptrs[1]) * NH + (kb - NH);
  }
  const float* wp = Wres + (size_t)kb * NH + j0 + lane;   // per-lane

  float a0 = 0.f, a1 = 0.f;
  float w[8], wn[8];
  #pragma unroll
  for (int i = 0; i < 8; ++i) w[i] = wp[(size_t)i * NH];

  #pragma unroll 1
  for (int kc = 0; kc < 128; kc += 8) {
    if (kc + 8 < 128) {                            // prefetch next weights
      #pragma unroll
      for (int i = 0; i < 8; ++i) wn[i] = wp[(size_t)(kc + 8 + i) * NH];
    }
    f4v q0[2], q1[2];
    #pragma unroll
    for (int i = 0; i < 2; ++i) {
      q0[i] = *(const f4v*)(p0 + kc + 4 * i);
      q1[i] = *(const f4v*)(p1 + kc + 4 * i);
    }
    #pragma unroll
    for (int i = 0; i < 8; ++i) {
      const float wv_ = w[i];
      a0 += q0[i >> 2][i & 3] * wv_;
      a1 += q1[i >> 2][i & 3] * wv_;
    }
    if (kc + 8 < 128) {
      #pragma unroll
      for (int i = 0; i < 8; ++i) w[i] = wn[i];
    }
  }

  // cross-wave reduce: red[16 w][2 b][64 j]
  smem[wv * 128 + 0 * 64 + lane] = a0;
  smem[wv * 128 + 1 * 64 + lane] = a1;
  __syncthreads();

  if (tid < 128) {
    const int bsel = tid >> 6, jloc = tid & 63;
    float v = bres[j0 + jloc];
    #pragma unroll
    for (int w2 = 0; w2 < 16; ++w2) v += smem[w2 * 128 + bsel * 64 + jloc];
    const int b = b0 + bsel, j = j0 + jloc;
    float hold = h[(size_t)b * NH + j];
    float hout = done ? hold : v;
    h[(size_t)b * NH + j] = hout;
    if (st < NSTEP - 1) {
      float hnv = hout + 0.01f * noise[(size_t)(st + 1) * (NB * NH) + (size_t)b * NH + j];
      hn_nxt[(size_t)b * NH + j] = hnv;
      hnT_nxt[((size_t)(j >> 1)) * 128 + b * 2 + (j & 1)] = hnv;
      const float* wrp = Wop + (size_t)j * NOPSN;
      float opo[8];
      #pragma unroll
      for (int o = 0; o < 8; ++o) opo[o] = hnv * wrp[o];
      #pragma unroll
      for (int off = 1; off <= 32; off <<= 1) {
        #pragma unroll
        for (int o = 0; o < 8; ++o) opo[o] += __shfl_xor(opo[o], off);
      }
      if ((tid & 63) == 0) {
        float* od = opp + ((size_t)(st + 1) * 16 + jg) * 512 + (size_t)b * 8;
        #pragma unroll
        for (int o = 0; o < 8; ++o) od[o] = opo[o];
      }
    } else {
      out[(size_t)b * NH + j] = hout;
    }
  }
}

extern "C" void kernel_launch(void* const* d_in, const int* in_sizes, int n_in,
                              void* d_out, int out_size, void* d_ws, size_t ws_size,
                              hipStream_t stream) {
  const float* s2a   = (const float*)d_in[0];
  const float* Wres  = (const float*)d_in[1];
  const float* bres  = (const float*)d_in[2];
  const float* Wop   = (const float*)d_in[3];
  const float* bop   = (const float*)d_in[4];
  const float* Wx    = (const float*)d_in[5];
  const float* bx    = (const float*)d_in[6];
  const float* noise = (const float*)d_in[7];
  float* outp = (float*)d_out;
  float* wsf  = (float*)d_ws;   // needs ~1.9 MB

  hipLaunchKernelGGL(init_kernel, dim3(64), dim3(1024), 0, stream,
                     noise, Wop, wsf);
  for (int st = 0; st < NSTEP; ++st) {
    hipLaunchKernelGGL(phaseA_kernel, dim3(512), dim3(1024), 0, stream,
                       Wx, bx, bop, wsf, st);
    hipLaunchKernelGGL(phaseC_kernel, dim3(512), dim3(1024), 0, stream,
                       s2a, Wres, bres, Wop, noise, outp, wsf, st);
  }
}

// Round 14
// 1669.694 us; speedup vs baseline: 1.0817x; 1.0772x over previous
//
#include <hip/hip_runtime.h>
#include <cstdint>
#include <cstddef>

// Problem constants
#define NB    64      // batch
#define NS    4096    // seq len
#define NH    1024    // hidden
#define NOPSN 8
#define NSTEP 10

// Workspace layout (float offsets), ~1.9 MB.
// hn/hnT double-buffered by step parity; hnT = k-pair interleave:
// element (k,b) at [(k>>1)*128 + b*2 + (k&1)]
#define OFF_HN0  0u
#define OFF_HN1  65536u
#define OFF_HT0  131072u
#define OFF_HT1  196608u
#define OFF_H    262144u
#define OFF_CAND 327680u   // cand [64 b][512 blk] float2 (val, idx-as-float)
#define OFF_OPP  393216u   // opp [10][16 jg][64 b][8 o]
#define OFF_CTRL 475136u   // ints: [2..11]=stopcnt[t]

typedef float f2v  __attribute__((ext_vector_type(2)));
typedef float f4v  __attribute__((ext_vector_type(4)));
typedef float f8v  __attribute__((ext_vector_type(8)));

__device__ __forceinline__ float bcastf(float v, int l) {
  return __int_as_float(__builtin_amdgcn_readlane(__float_as_int(v), l));
}

// ============ INIT: hn(0)=0.01*noise[0], hnT(0), h=0, opp[0], ctrl=0 ======
// grid 64 (block = b), 1024 threads (thread = j). Wave wv == jg.
__global__ void __launch_bounds__(1024)
init_kernel(const float* __restrict__ noise, const float* __restrict__ Wop,
            float* __restrict__ wsf)
{
  const int b = blockIdx.x, j = threadIdx.x;
  const int lane = j & 63, jg = j >> 6;
  int* ctrl = (int*)(wsf + OFF_CTRL);
  if (b == 0 && j < NSTEP) ctrl[2 + j] = 0;

  float hv = 0.01f * noise[(size_t)b * NH + j];
  (wsf + OFF_HN0)[(size_t)b * NH + j] = hv;
  (wsf + OFF_HT0)[((size_t)(j >> 1)) * 128 + b * 2 + (j & 1)] = hv;
  (wsf + OFF_H)[(size_t)b * NH + j] = 0.f;

  const float* wrp = Wop + (size_t)j * NOPSN;
  float opo[8];
  #pragma unroll
  for (int o = 0; o < 8; ++o) opo[o] = hv * wrp[o];
  #pragma unroll
  for (int off = 1; off <= 32; off <<= 1) {
    #pragma unroll
    for (int o = 0; o < 8; ++o) opo[o] += __shfl_xor(opo[o], off);
  }
  if (lane == 0) {
    float* od = (wsf + OFF_OPP) + (size_t)jg * 512 + (size_t)b * 8;
    #pragma unroll
    for (int o = 0; o < 8; ++o) od[o] = opo[o];
  }
}

// ============ PHASE A: x_logits[8 s][64 b] + cand + op-argmax =============
// grid 512 (block = 8 s-cols), 1024 thr, 32 KB LDS -> 2 blocks/CU,
// 8 waves/SIMD (2x the TLP of R10). lane = b; wave = 64-k slice.
__global__ void __launch_bounds__(1024, 8)
phaseA_kernel(const float* __restrict__ Wx, const float* __restrict__ bx,
              const float* __restrict__ bop, float* __restrict__ wsf, int st)
{
  __shared__ float smem[8192];   // 32 KB: [16 w][8 s][64 b]
  int* ctrl = (int*)(wsf + OFF_CTRL);
  float* __restrict__ opp = wsf + OFF_OPP;
  const float* __restrict__ hnT_cur = wsf + ((st & 1) ? OFF_HT1 : OFF_HT0);

  const int tid = threadIdx.x, blk = blockIdx.x;
  const int lane = tid & 63;
  const int wv = __builtin_amdgcn_readfirstlane(tid >> 6);
  const int s0A = blk << 3;
  const int kbaseA = wv << 6;

  const float2* hb = (const float2*)hnT_cur + ((size_t)(kbaseA >> 1)) * 64 + lane;

  // op-argmax for step st (blocks 0..63, wave 0)
  if (blk < NB && tid < 64) {
    const float* ob = opp + (size_t)st * 8192 + (size_t)blk * 8;
    const int o = lane & 7, jgb = lane >> 3;
    float v = ob[(size_t)jgb * 512 + o] + ob[(size_t)(jgb + 8) * 512 + o];
    v += __shfl_xor(v, 8);
    v += __shfl_xor(v, 16);
    v += __shfl_xor(v, 32);
    v += bop[o];
    float bv = bcastf(v, 0); int bo = 0;
    #pragma unroll
    for (int oo = 1; oo < 8; ++oo) {
      float vo = bcastf(v, oo);
      if (vo > bv) { bv = vo; bo = oo; }            // strict > : first-max
    }
    if (lane == 0 && bo == 0) atomicAdd(&ctrl[2 + st], 1);
  }

  float acc[8];
  #pragma unroll
  for (int s = 0; s < 8; ++s) acc[s] = 0.f;

  #pragma unroll 1
  for (int c = 0; c < 4; ++c) {
    float2 hh[8];
    #pragma unroll
    for (int i = 0; i < 8; ++i) hh[i] = hb[(size_t)(c * 8 + i) * 64];
    #pragma unroll
    for (int i = 0; i < 8; ++i) {
      const int k = kbaseA + (c * 8 + i) * 2;
      const f8v w0 = *(const f8v*)(Wx + (size_t)k * NS + s0A);
      const f8v w1 = *(const f8v*)(Wx + (size_t)(k + 1) * NS + s0A);
      #pragma unroll
      for (int s = 0; s < 8; ++s)
        acc[s] += w0[s] * hh[i].x + w1[s] * hh[i].y;
    }
  }

  // cross-wave K reduction: red[16 w][8 s][64 b]
  #pragma unroll
  for (int s = 0; s < 8; ++s)
    smem[wv * 512 + s * 64 + lane] = acc[s];
  __syncthreads();
  {
    const int s = tid >> 6, b = tid & 63;           // s in [0,16), valid < 8
    float val = 0.f;
    if (s < 8) {
      val = bx[s0A + s];
      #pragma unroll
      for (int w = 0; w < 16; ++w) val += smem[w * 512 + s * 64 + b];
    }
    __syncthreads();
    if (s < 8) smem[s * 64 + b] = val;
    __syncthreads();
    if (tid < 64) {
      const int bb = tid;
      float bv = smem[bb]; int bs = 0;
      #pragma unroll
      for (int s2 = 1; s2 < 8; ++s2) {
        float v2 = smem[s2 * 64 + bb];
        if (v2 > bv) { bv = v2; bs = s2; }          // ascending s: first-max
      }
      float2* cp = (float2*)(wsf + OFF_CAND);
      cp[bb * 512 + blk] = make_float2(bv, __int_as_float(s0A + bs));
    }
  }
}

// ============ PHASE C: h_new + freeze + next hn/hnT/opp (+ out) ===========
// grid 512: block (jg: 64 j, bg: 2 b), 1024 thr, 8 KB LDS -> 2 blocks/CU.
__global__ void __launch_bounds__(1024, 8)
phaseC_kernel(const float* __restrict__ s2a,  const float* __restrict__ Wres,
              const float* __restrict__ bres, const float* __restrict__ Wop,
              const float* __restrict__ noise, float* __restrict__ out,
              float* __restrict__ wsf, int st)
{
  __shared__ float smem[2048];   // 8 KB: [16 w][2 b][64 j]
  int* ctrl = (int*)(wsf + OFF_CTRL);
  float* __restrict__ h   = wsf + OFF_H;
  float* __restrict__ opp = wsf + OFF_OPP;
  const float* __restrict__ hn_cur = wsf + ((st & 1) ? OFF_HN1 : OFF_HN0);
  float* __restrict__       hn_nxt = wsf + ((st & 1) ? OFF_HN0 : OFF_HN1);
  float* __restrict__      hnT_nxt = wsf + ((st & 1) ? OFF_HT0 : OFF_HT1);

  const int tid = threadIdx.x, blk = blockIdx.x;
  const int lane = tid & 63;
  const int wv = __builtin_amdgcn_readfirstlane(tid >> 6);
  const int jg = blk & 15, bg = blk >> 4;          // bg in [0,32)
  const int j0 = jg << 6, b0 = bg << 1;            // 2 b per block

  int ptrs[2] = {0, 0};
  if (wv >= 8) {                                   // only s2a half needs ptrs
    const float2* cp = (const float2*)(wsf + OFF_CAND);
    #pragma unroll
    for (int i = 0; i < 2; ++i) {
      const float2* row = cp + (size_t)(b0 + i) * 512;
      float2 c0 = row[lane];
      float bv = c0.x; int bi = __float_as_int(c0.y);
      #pragma unroll
      for (int q = 1; q < 8; ++q) {
        float2 c = row[q * 64 + lane];
        if (c.x > bv) { bv = c.x; bi = __float_as_int(c.y); }
      }
      #pragma unroll
      for (int off = 1; off <= 32; off <<= 1) {
        float ov = __shfl_xor(bv, off);
        int   oi = __shfl_xor(bi, off);
        if (ov > bv || (ov == bv && oi < bi)) { bv = ov; bi = oi; }
      }
      ptrs[i] = __builtin_amdgcn_readfirstlane(bi);
    }
  }
  int done = 0;
  for (int tt = 0; tt < st; ++tt) done |= (ctrl[2 + tt] == NB) ? 1 : 0;

  const int kb = wv << 7;                          // 128 k per wave
  const float *p0, *p1;                            // wave-uniform bases
  if (wv < 8) {
    p0 = hn_cur + (size_t)(b0 + 0) * NH + kb;
    p1 = hn_cur + (size_t)(b0 + 1) * NH + kb;
  } else {
    p0 = s2a + ((size_t)(b0 + 0) * NS + ptrs[0]) * NH + (kb - NH);
    p1 = s2a + ((size_t)(b0 + 1) * NS + ptrs[1]) * NH + (kb - NH);
  }
  const float* wp = Wres + (size_t)kb * NH + j0 + lane;   // per-lane

  float a0 = 0.f, a1 = 0.f;

  #pragma unroll 1
  for (int kc = 0; kc < 128; kc += 8) {
    float w[8];
    f4v q0[2], q1[2];
    #pragma unroll
    for (int i = 0; i < 8; ++i) w[i] = wp[(size_t)(kc + i) * NH];
    #pragma unroll
    for (int i = 0; i < 2; ++i) {
      q0[i] = *(const f4v*)(p0 + kc + 4 * i);
      q1[i] = *(const f4v*)(p1 + kc + 4 * i);
    }
    #pragma unroll
    for (int i = 0; i < 8; ++i) {
      const float wv_ = w[i];
      a0 += q0[i >> 2][i & 3] * wv_;
      a1 += q1[i >> 2][i & 3] * wv_;
    }
  }

  // cross-wave reduce: red[16 w][2 b][64 j]
  smem[wv * 128 + 0 * 64 + lane] = a0;
  smem[wv * 128 + 1 * 64 + lane] = a1;
  __syncthreads();

  if (tid < 128) {
    const int bsel = tid >> 6, jloc = tid & 63;
    float v = bres[j0 + jloc];
    #pragma unroll
    for (int w = 0; w < 16; ++w) v += smem[w * 128 + bsel * 64 + jloc];
    const int b = b0 + bsel, j = j0 + jloc;
    float hold = h[(size_t)b * NH + j];
    float hout = done ? hold : v;
    h[(size_t)b * NH + j] = hout;
    if (st < NSTEP - 1) {
      float hnv = hout + 0.01f * noise[(size_t)(st + 1) * (NB * NH) + (size_t)b * NH + j];
      hn_nxt[(size_t)b * NH + j] = hnv;
      hnT_nxt[((size_t)(j >> 1)) * 128 + b * 2 + (j & 1)] = hnv;
      const float* wrp = Wop + (size_t)j * NOPSN;
      float opo[8];
      #pragma unroll
      for (int o = 0; o < 8; ++o) opo[o] = hnv * wrp[o];
      #pragma unroll
      for (int off = 1; off <= 32; off <<= 1) {
        #pragma unroll
        for (int o = 0; o < 8; ++o) opo[o] += __shfl_xor(opo[o], off);
      }
      if ((tid & 63) == 0) {
        float* od = opp + ((size_t)(st + 1) * 16 + jg) * 512 + (size_t)b * 8;
        #pragma unroll
        for (int o = 0; o < 8; ++o) od[o] = opo[o];
      }
    } else {
      out[(size_t)b * NH + j] = hout;
    }
  }
}

extern "C" void kernel_launch(void* const* d_in, const int* in_sizes, int n_in,
                              void* d_out, int out_size, void* d_ws, size_t ws_size,
                              hipStream_t stream) {
  const float* s2a   = (const float*)d_in[0];
  const float* Wres  = (const float*)d_in[1];
  const float* bres  = (const float*)d_in[2];
  const float* Wop   = (const float*)d_in[3];
  const float* bop   = (const float*)d_in[4];
  const float* Wx    = (const float*)d_in[5];
  const float* bx    = (const float*)d_in[6];
  const float* noise = (const float*)d_in[7];
  float* outp = (float*)d_out;
  float* wsf  = (float*)d_ws;   // needs ~1.9 MB

  hipLaunchKernelGGL(init_kernel, dim3(64), dim3(1024), 0, stream,
                     noise, Wop, wsf);
  for (int st = 0; st < NSTEP; ++st) {
    hipLaunchKernelGGL(phaseA_kernel, dim3(512), dim3(1024), 0, stream,
                       Wx, bx, bop, wsf, st);
    hipLaunchKernelGGL(phaseC_kernel, dim3(512), dim3(1024), 0, stream,
                       s2a, Wres, bres, Wop, noise, outp, wsf, st);
  }
}